// Round 3
// baseline (218.598 us; speedup 1.0000x reference)
//
#include <hip/hip_runtime.h>
#include <hip/hip_bf16.h>

#define SEQ_LEN  8192
#define HIDDEN   1024
#define NUM_SPANS 4096
#define MAX_W    32
#define NEG_INF  -1e9f

// One block per span, 256 threads.
// __launch_bounds__(256, 2): relax the VGPR cap (~256) so the compiler keeps
// the 8-load batches of phase 3 (and phase 1's unrolled loads) in flight.
// Round-2 evidence: at the default 8-waves/SIMD target the compiler pinned
// VGPR=36 and serialized every load (1-deep chain, 110+ us latency-bound).
__global__ __launch_bounds__(256, 2) void span_repr_kernel(
    const float* __restrict__ emb,      // (SEQ_LEN, HIDDEN)
    const int* __restrict__ starts,     // (NUM_SPANS,)
    const int* __restrict__ ends,       // (NUM_SPANS,)
    const float* __restrict__ attn_w,   // (HIDDEN,)
    const float* __restrict__ attn_b,   // (1,)
    float* __restrict__ out)            // (NUM_SPANS, 3*HIDDEN)
{
    const int s   = blockIdx.x;
    const int tid = threadIdx.x;

    __shared__ float s_scores[MAX_W];
    __shared__ alignas(16) float s_wt[MAX_W];

    const int start = starts[s];
    const int end   = ends[s];
    const float bias = attn_b[0];

    // ---------- Prefetch start/end rows (latency hides behind phase 1) ----
    const float4* __restrict__ srow = (const float4*)(emb + (size_t)start * HIDDEN);
    const float4* __restrict__ erow = (const float4*)(emb + (size_t)end   * HIDDEN);
    float4 sv = srow[tid];
    float4 ev = erow[tid];

    // ---------- Phase 1: scores ----------
    const int w = tid >> 3;   // 0..31 position within span
    const int g = tid & 7;    // 0..7 chunk of 128 elements
    const int pos = start + w;
    const bool valid = (pos <= end);

    float partial = 0.0f;
    {
        // clamp invalid positions onto the end row: loads stay in-bounds and
        // L1-hot; the result is discarded below for invalid lanes.
        const int pc = valid ? pos : end;
        const float4* __restrict__ row = (const float4*)(emb + (size_t)pc * HIDDEN);
        const float4* __restrict__ wv  = (const float4*)attn_w;
        const int base = g * 32;  // float4 index: g*128 floats
        #pragma unroll
        for (int i = 0; i < 32; ++i) {
            float4 a = row[base + i];
            float4 b = wv[base + i];
            partial += a.x * b.x + a.y * b.y + a.z * b.z + a.w * b.w;
        }
    }
    // reduce the 8 chunk-partials (contiguous lanes within one wave)
    partial += __shfl_down(partial, 4, 8);
    partial += __shfl_down(partial, 2, 8);
    partial += __shfl_down(partial, 1, 8);
    if (g == 0) s_scores[w] = valid ? (partial + bias) : NEG_INF;
    __syncthreads();

    // ---------- Phase 2: masked softmax over 32 positions ----------
    if (tid < 32) {
        float sc = s_scores[tid];
        float m = sc;
        #pragma unroll
        for (int off = 16; off > 0; off >>= 1)
            m = fmaxf(m, __shfl_xor(m, off, 32));
        float e = expf(sc - m);         // invalid: exp(-1e9 - m) == exactly 0
        float sum = e;
        #pragma unroll
        for (int off = 16; off > 0; off >>= 1)
            sum += __shfl_xor(sum, off, 32);
        s_wt[tid] = e / sum;            // exactly 0 for invalid positions
    }
    __syncthreads();

    // ---------- Phase 3: outputs ----------
    float4* __restrict__ out4 = (float4*)(out + (size_t)s * (3 * HIDDEN));
    out4[tid]       = sv;   // 256 float4 = 1024 floats, fully coalesced
    out4[256 + tid] = ev;

    float4 acc0 = make_float4(0.f, 0.f, 0.f, 0.f);
    float4 acc1 = make_float4(0.f, 0.f, 0.f, 0.f);

    const int wmax = end - start;             // 0..31 (inclusive width-1)
    const int nw8  = (wmax + 8) & ~7;         // 8,16,24,32

    const float4* __restrict__ embr = (const float4*)emb;

    #pragma unroll 1
    for (int ww = 0; ww < nw8; ww += 8) {
        // weights (LDS, 16B-aligned since ww % 8 == 0)
        const float4 wA = *(const float4*)&s_wt[ww];
        const float4 wB = *(const float4*)&s_wt[ww + 4];

        // 8 independent row loads; padded positions clamp onto the end row
        // (L1-hot duplicate, zero weight) instead of fetching new rows.
        const int p0 = min(ww + 0, wmax), p1 = min(ww + 1, wmax);
        const int p2 = min(ww + 2, wmax), p3 = min(ww + 3, wmax);
        const int p4 = min(ww + 4, wmax), p5 = min(ww + 5, wmax);
        const int p6 = min(ww + 6, wmax), p7 = min(ww + 7, wmax);
        const size_t rb = (size_t)start * 256 + tid;  // float4 units

        float4 a0 = embr[rb + (size_t)p0 * 256];
        float4 a1 = embr[rb + (size_t)p1 * 256];
        float4 a2 = embr[rb + (size_t)p2 * 256];
        float4 a3 = embr[rb + (size_t)p3 * 256];
        float4 a4 = embr[rb + (size_t)p4 * 256];
        float4 a5 = embr[rb + (size_t)p5 * 256];
        float4 a6 = embr[rb + (size_t)p6 * 256];
        float4 a7 = embr[rb + (size_t)p7 * 256];

        acc0.x += wA.x * a0.x; acc0.y += wA.x * a0.y; acc0.z += wA.x * a0.z; acc0.w += wA.x * a0.w;
        acc1.x += wA.y * a1.x; acc1.y += wA.y * a1.y; acc1.z += wA.y * a1.z; acc1.w += wA.y * a1.w;
        acc0.x += wA.z * a2.x; acc0.y += wA.z * a2.y; acc0.z += wA.z * a2.z; acc0.w += wA.z * a2.w;
        acc1.x += wA.w * a3.x; acc1.y += wA.w * a3.y; acc1.z += wA.w * a3.z; acc1.w += wA.w * a3.w;
        acc0.x += wB.x * a4.x; acc0.y += wB.x * a4.y; acc0.z += wB.x * a4.z; acc0.w += wB.x * a4.w;
        acc1.x += wB.y * a5.x; acc1.y += wB.y * a5.y; acc1.z += wB.y * a5.z; acc1.w += wB.y * a5.w;
        acc0.x += wB.z * a6.x; acc0.y += wB.z * a6.y; acc0.z += wB.z * a6.z; acc0.w += wB.z * a6.w;
        acc1.x += wB.w * a7.x; acc1.y += wB.w * a7.y; acc1.z += wB.w * a7.z; acc1.w += wB.w * a7.w;
    }

    float4 acc = make_float4(acc0.x + acc1.x, acc0.y + acc1.y,
                             acc0.z + acc1.z, acc0.w + acc1.w);
    out4[512 + tid] = acc;
}

extern "C" void kernel_launch(void* const* d_in, const int* in_sizes, int n_in,
                              void* d_out, int out_size, void* d_ws, size_t ws_size,
                              hipStream_t stream) {
    const float* emb    = (const float*)d_in[0];
    const int*   starts = (const int*)d_in[1];
    const int*   ends   = (const int*)d_in[2];
    const float* attn_w = (const float*)d_in[3];
    const float* attn_b = (const float*)d_in[4];
    float* out = (float*)d_out;

    span_repr_kernel<<<NUM_SPANS, 256, 0, stream>>>(emb, starts, ends, attn_w, attn_b, out);
}

// Round 4
// 124.811 us; speedup vs baseline: 1.7514x; 1.7514x over previous
//
#include <hip/hip_runtime.h>
#include <hip/hip_bf16.h>
#include <math.h>

#define SEQ_LEN  8192
#define HIDDEN   1024
#define NUM_SPANS 4096
#define MAX_W    32
#define NEG_INF  -1e9f

__device__ __forceinline__ float dot4(float4 a, float4 b) {
    return a.x * b.x + a.y * b.y + a.z * b.z + a.w * b.w;
}

// One block (256 threads = 4 waves) per span. Flash-style single pass over the
// span rows in chunks of 4:
//   - wave w owns row w of the chunk; its 64 lanes load the 4 KB row with
//     4 coalesced float4 loads (lane stride 16 B), dot against attn_w slices
//     held in registers, butterfly-reduce -> score (no LDS round trip).
//   - rows are staged to LDS (double-buffered) for the column-major weighted
//     accumulate; online softmax (m, l, alpha) makes it one pass, one barrier
//     per chunk.
// Round-3 evidence: compiler refuses to keep register load batches in flight
// (VGPR pinned at 36); this structure makes the latency hiding and the
// coalescing structural rather than scheduler-dependent.
__global__ __launch_bounds__(256, 4) void span_repr_kernel(
    const float* __restrict__ emb,      // (SEQ_LEN, HIDDEN)
    const int* __restrict__ starts,     // (NUM_SPANS,)
    const int* __restrict__ ends,       // (NUM_SPANS,)
    const float* __restrict__ attn_w,   // (HIDDEN,)
    const float* __restrict__ attn_b,   // (1,)
    float* __restrict__ out)            // (NUM_SPANS, 3*HIDDEN)
{
    const int s   = blockIdx.x;
    const int tid = threadIdx.x;
    const int w2  = tid >> 6;    // wave id 0..3  == row-in-chunk
    const int c   = tid & 63;    // lane  0..63

    __shared__ float4 buf[2][4][256];   // [parity][row][col]  2 x 16 KB
    __shared__ float  cscore[2][4];     // per-chunk row scores

    const int start = starts[s];
    const int end   = ends[s];
    const int wmax  = end - start;      // inclusive width-1, 0..31
    const float bias = attn_b[0];

    const float4* __restrict__ embr = (const float4*)emb;

    // prefetch start/end rows (latency hidden behind preamble)
    float4 sv = embr[(size_t)start * 256 + tid];
    float4 ev = embr[(size_t)end   * 256 + tid];

    // per-lane attn_w slice: float4 indices c, c+64, c+128, c+192
    const float4* __restrict__ wv4 = (const float4*)attn_w;
    const float4 wv0 = wv4[c];
    const float4 wv1 = wv4[c + 64];
    const float4 wv2 = wv4[c + 128];
    const float4 wv3 = wv4[c + 192];

    const int nc = (wmax >> 2) + 1;     // chunks of 4 rows: 1..8

    // ---------------- preamble: stage chunk 0 + its scores ----------------
    {
        const int r  = w2;                       // row index within span
        const int rc = min(r, wmax);             // clamp: dup of end row, wt=0
        const float4* __restrict__ row = embr + (size_t)(start + rc) * 256;
        float4 r0 = row[c];
        float4 r1 = row[c + 64];
        float4 r2 = row[c + 128];
        float4 r3 = row[c + 192];
        float p = dot4(r0, wv0) + dot4(r1, wv1) + dot4(r2, wv2) + dot4(r3, wv3);
        #pragma unroll
        for (int off = 32; off > 0; off >>= 1)
            p += __shfl_xor(p, off, 64);
        if (c == 0) cscore[0][w2] = (r <= wmax) ? (p + bias) : NEG_INF;
        buf[0][w2][c]       = r0;
        buf[0][w2][c + 64]  = r1;
        buf[0][w2][c + 128] = r2;
        buf[0][w2][c + 192] = r3;
    }

    // write start/end rows while the preamble drains
    float4* __restrict__ out4 = (float4*)(out + (size_t)s * (3 * HIDDEN));
    out4[tid]       = sv;
    out4[256 + tid] = ev;

    __syncthreads();

    float4 acc = make_float4(0.f, 0.f, 0.f, 0.f);
    float m = -INFINITY;
    float l = 0.0f;

    for (int ck = 0; ck < nc; ++ck) {
        const int par = ck & 1;
        const int pn  = par ^ 1;
        const bool more = (ck + 1 < nc);

        // -------- issue next chunk's global loads (batched, in flight) ----
        float4 r0, r1, r2, r3;
        if (more) {
            const int r  = (ck + 1) * 4 + w2;
            const int rc = min(r, wmax);
            const float4* __restrict__ row = embr + (size_t)(start + rc) * 256;
            r0 = row[c];
            r1 = row[c + 64];
            r2 = row[c + 128];
            r3 = row[c + 192];
            __builtin_amdgcn_sched_barrier(0);   // pin loads above the compute
        }

        // -------- consume chunk ck: online softmax + weighted accumulate --
        const float s0 = cscore[par][0];
        const float s1 = cscore[par][1];
        const float s2 = cscore[par][2];
        const float s3 = cscore[par][3];
        const float cm = fmaxf(fmaxf(s0, s1), fmaxf(s2, s3));
        const float mn = fmaxf(m, cm);
        const float alpha = __expf(m - mn);      // m=-inf first chunk -> 0
        const float e0 = __expf(s0 - mn);        // masked (-1e9) -> exactly 0
        const float e1 = __expf(s1 - mn);
        const float e2 = __expf(s2 - mn);
        const float e3 = __expf(s3 - mn);
        l = l * alpha + (e0 + e1 + e2 + e3);

        const float4 b0 = buf[par][0][tid];
        const float4 b1 = buf[par][1][tid];
        const float4 b2 = buf[par][2][tid];
        const float4 b3 = buf[par][3][tid];
        acc.x = acc.x * alpha + e0 * b0.x + e1 * b1.x + e2 * b2.x + e3 * b3.x;
        acc.y = acc.y * alpha + e0 * b0.y + e1 * b1.y + e2 * b2.y + e3 * b3.y;
        acc.z = acc.z * alpha + e0 * b0.z + e1 * b1.z + e2 * b2.z + e3 * b3.z;
        acc.w = acc.w * alpha + e0 * b0.w + e1 * b1.w + e2 * b2.w + e3 * b3.w;
        m = mn;

        // -------- score + stage the prefetched chunk ----------------------
        if (more) {
            float p = dot4(r0, wv0) + dot4(r1, wv1) + dot4(r2, wv2) + dot4(r3, wv3);
            #pragma unroll
            for (int off = 32; off > 0; off >>= 1)
                p += __shfl_xor(p, off, 64);
            const int r = (ck + 1) * 4 + w2;
            if (c == 0) cscore[pn][w2] = (r <= wmax) ? (p + bias) : NEG_INF;
            buf[pn][w2][c]       = r0;
            buf[pn][w2][c + 64]  = r1;
            buf[pn][w2][c + 128] = r2;
            buf[pn][w2][c + 192] = r3;
        }
        __syncthreads();
    }

    const float inv = 1.0f / l;                  // row 0 always valid -> l > 0
    out4[512 + tid] = make_float4(acc.x * inv, acc.y * inv,
                                  acc.z * inv, acc.w * inv);
}

extern "C" void kernel_launch(void* const* d_in, const int* in_sizes, int n_in,
                              void* d_out, int out_size, void* d_ws, size_t ws_size,
                              hipStream_t stream) {
    const float* emb    = (const float*)d_in[0];
    const int*   starts = (const int*)d_in[1];
    const int*   ends   = (const int*)d_in[2];
    const float* attn_w = (const float*)d_in[3];
    const float* attn_b = (const float*)d_in[4];
    float* out = (float*)d_out;

    span_repr_kernel<<<NUM_SPANS, 256, 0, stream>>>(emb, starts, ends, attn_w, attn_b, out);
}